// Round 4
// baseline (192.053 us; speedup 1.0000x reference)
//
#include <hip/hip_runtime.h>
#include <hip/hip_bf16.h>

#define B_ 64
#define L_ 512
#define H_ 1024
#define EPS_ 1e-13f

typedef unsigned short u16;
typedef __attribute__((ext_vector_type(8))) short s16x8;
typedef __attribute__((ext_vector_type(4))) float f32x4;

__device__ __forceinline__ u16 f2bf(float f) {
  __hip_bfloat16 h = __float2bfloat16(f);
  union { __hip_bfloat16 h; u16 u; } c; c.h = h; return c.u;
}

// ---- Kernel 1: transpose+convert X f32 [B,L,H] -> XT bf16 [B,H,L] ----
__global__ __launch_bounds__(256) void transpose_x(const float* __restrict__ X,
                                                   u16* __restrict__ XT) {
  const int bid = blockIdx.x;
  const int lt = bid & 7;          // L/64
  const int ht = (bid >> 3) & 15;  // H/64
  const int b  = bid >> 7;
  const int l0 = lt * 64, h0 = ht * 64;

  __shared__ __align__(16) u16 tile[64 * 64];
  const int t = threadIdx.x;
  const int cg = t & 7;
  const int rr = t >> 3;

#pragma unroll
  for (int it = 0; it < 2; ++it) {
    int r = rr + it * 32;
    size_t gidx = ((size_t)(b * L_ + l0 + r)) * H_ + h0 + cg * 8;
    float4 u0 = *(const float4*)(X + gidx);
    float4 u1 = *(const float4*)(X + gidx + 4);
    union { u16 u[8]; uint4 v; } w;
    w.u[0] = f2bf(u0.x); w.u[1] = f2bf(u0.y); w.u[2] = f2bf(u0.z); w.u[3] = f2bf(u0.w);
    w.u[4] = f2bf(u1.x); w.u[5] = f2bf(u1.y); w.u[6] = f2bf(u1.z); w.u[7] = f2bf(u1.w);
    int g = cg ^ (r & 7) ^ ((r >> 3) & 7);
    *(uint4*)&tile[r * 64 + g * 8] = w.v;
  }
  __syncthreads();
#pragma unroll
  for (int it = 0; it < 2; ++it) {
    int hc = rr + it * 32;
    union { u16 u[8]; uint4 v; } e;
#pragma unroll
    for (int m2 = 0; m2 < 8; ++m2) {
      int r = cg * 8 + m2;
      int g = (hc >> 3) ^ (r & 7) ^ ((r >> 3) & 7);
      e.u[m2] = tile[r * 64 + g * 8 + (hc & 7)];
    }
    *(uint4*)(XT + ((size_t)(b * H_ + h0 + hc)) * L_ + l0 + cg * 8) = e.v;
  }
}

// ---- Kernel 2: fused softmax-stats + GEMM  out = softmax(att)*renorm @ X ----
// 256x256 tile, 8 waves, 2-barrier m97-style core. A is reg-staged from att
// f32 with inline exp(a-m)*s (softmax row-sum==1 so renorm is a row scalar);
// B via global_load_lds from XT. XOR-swizzled LDS both sides; XCD-swizzled grid.
__global__ __launch_bounds__(512, 2) void gemm_fused(const float* __restrict__ att,
                                                     const float* __restrict__ mask,
                                                     const u16* __restrict__ XT,
                                                     float* __restrict__ out) {
  // grid=512, 512%8==0 -> bijective XCD swizzle; all 8 blocks of a batch on one XCD.
  const int swz = (blockIdx.x & 7) * 64 + (blockIdx.x >> 3);
  const int b  = swz >> 3;
  const int mt = (swz >> 2) & 1;  // M=512 -> 2 tiles of 256
  const int nt = swz & 3;         // N=1024 -> 4 tiles of 256

  __shared__ __align__(16) u16 lA[256 * 64];
  __shared__ __align__(16) u16 lB[256 * 64];
  __shared__ float2 lstats[256];  // per-row {m, s}

  const int t = threadIdx.x;
  const int lane = t & 63;
  const int w = t >> 6;               // 8 waves
  const int wm = w >> 2, wn = w & 3;  // 2x4 wave grid, 128x64 per wave

  const float* gA = att + ((size_t)b * L_ + mt * 256) * L_;  // 256 rows x 512 f32
  const u16* gB = XT + ((size_t)b * H_ + nt * 256) * L_;

  // ---- stats prologue: one wave per row, rows w, w+8, ... ----
  for (int r = w; r < 256; r += 8) {
    const float* rp = gA + (size_t)r * L_ + lane * 8;
    float4 u0 = *(const float4*)rp;
    float4 u1 = *(const float4*)(rp + 4);
    float a[8] = {u0.x, u0.y, u0.z, u0.w, u1.x, u1.y, u1.z, u1.w};
    float m = a[0];
#pragma unroll
    for (int j = 1; j < 8; ++j) m = fmaxf(m, a[j]);
#pragma unroll
    for (int off = 32; off > 0; off >>= 1) m = fmaxf(m, __shfl_xor(m, off));
    float z = 0.f;
#pragma unroll
    for (int j = 0; j < 8; ++j) z += __expf(a[j] - m);
#pragma unroll
    for (int off = 32; off > 0; off >>= 1) z += __shfl_xor(z, off);
    if (lane == 0) {
      float mk = mask[b * L_ + mt * 256 + r];
      float s = (1.0f / z) * (mk / (mk + EPS_));  // softmax row-sum == 1
      lstats[r] = make_float2(m, s);
    }
  }
  __syncthreads();

  f32x4 acc[8][4] = {};

  const int srow = t >> 3;         // 0..63
  const int slot = t & 7;          // 8 x 16B slots per 128B row
  const int sbyte = slot << 4;

  for (int kt = 0; kt < L_; kt += 64) {
    // B: async global->LDS, linear dest + inverse-swizzled source
#pragma unroll
    for (int q = 0; q < 4; ++q) {
      int r = q * 64 + srow;
      int sc = sbyte ^ ((r & 7) << 4);
      const u16* gpB = gB + (size_t)r * L_ + kt + (sc >> 1);
      char* lpB = (char*)lB + q * 8192 + w * 1024;
      __builtin_amdgcn_global_load_lds((const __attribute__((address_space(1))) unsigned*)gpB,
                                       (__attribute__((address_space(3))) unsigned*)lpB, 16, 0, 0);
    }
    // A: reg-staged att f32 -> exp(a-m)*s -> bf16, swizzled ds_write_b128
#pragma unroll
    for (int q = 0; q < 4; ++q) {
      int r = q * 64 + srow;
      const float* rp = gA + (size_t)r * L_ + kt + slot * 8;
      float4 u0 = *(const float4*)rp;
      float4 u1 = *(const float4*)(rp + 4);
      float2 ms = lstats[r];
      union { u16 u[8]; uint4 v; } pk;
      pk.u[0] = f2bf(__expf(u0.x - ms.x) * ms.y);
      pk.u[1] = f2bf(__expf(u0.y - ms.x) * ms.y);
      pk.u[2] = f2bf(__expf(u0.z - ms.x) * ms.y);
      pk.u[3] = f2bf(__expf(u0.w - ms.x) * ms.y);
      pk.u[4] = f2bf(__expf(u1.x - ms.x) * ms.y);
      pk.u[5] = f2bf(__expf(u1.y - ms.x) * ms.y);
      pk.u[6] = f2bf(__expf(u1.z - ms.x) * ms.y);
      pk.u[7] = f2bf(__expf(u1.w - ms.x) * ms.y);
      *(uint4*)((char*)lA + r * 128 + (sbyte ^ ((r & 7) << 4))) = pk.v;
    }
    __syncthreads();
#pragma unroll
    for (int ks = 0; ks < 2; ++ks) {
      const int kb = ks * 64 + ((lane >> 4) << 4);
      s16x8 af[8], bfv[4];
#pragma unroll
      for (int mf = 0; mf < 8; ++mf) {
        int r = wm * 128 + mf * 16 + (lane & 15);
        af[mf] = *(const s16x8*)((const char*)lA + r * 128 + (kb ^ ((r & 7) << 4)));
      }
#pragma unroll
      for (int nf = 0; nf < 4; ++nf) {
        int r = wn * 64 + nf * 16 + (lane & 15);
        bfv[nf] = *(const s16x8*)((const char*)lB + r * 128 + (kb ^ ((r & 7) << 4)));
      }
#pragma unroll
      for (int mf = 0; mf < 8; ++mf)
#pragma unroll
        for (int nf = 0; nf < 4; ++nf)
          acc[mf][nf] = __builtin_amdgcn_mfma_f32_16x16x32_bf16(af[mf], bfv[nf], acc[mf][nf], 0, 0, 0);
    }
    __syncthreads();
  }

  // C/D layout: col=lane&15, row=(lane>>4)*4+reg  [verified m89/m91]
  const int orow0 = mt * 256 + wm * 128 + ((lane >> 4) << 2);
  const int ocol0 = nt * 256 + wn * 64 + (lane & 15);
#pragma unroll
  for (int mf = 0; mf < 8; ++mf)
#pragma unroll
    for (int nf = 0; nf < 4; ++nf)
#pragma unroll
      for (int j = 0; j < 4; ++j) {
        int row = orow0 + mf * 16 + j;
        int col = ocol0 + nf * 16;
        out[((size_t)b * L_ + row) * H_ + col] = acc[mf][nf][j];
      }
}

extern "C" void kernel_launch(void* const* d_in, const int* in_sizes, int n_in,
                              void* d_out, int out_size, void* d_ws, size_t ws_size,
                              hipStream_t stream) {
  (void)in_sizes; (void)n_in; (void)out_size; (void)ws_size;
  const float* sent = (const float*)d_in[0];  // [B, L, H] f32
  const float* mask = (const float*)d_in[1];  // [B, L]    f32
  const float* att  = (const float*)d_in[2];  // [B, L, L] f32
  u16* XT = (u16*)d_ws;                       // [B, H, L] bf16 (64 MiB)
  float* outp = (float*)d_out;                // [B, L, H] f32

  transpose_x<<<B_ * (H_ / 64) * (L_ / 64), 256, 0, stream>>>(sent, XT);
  gemm_fused<<<B_ * 2 * 4, 512, 0, stream>>>(att, mask, XT, outp);
}

// Round 5
// 113.737 us; speedup vs baseline: 1.6886x; 1.6886x over previous
//
#include <hip/hip_runtime.h>
#include <hip/hip_bf16.h>

#define B_ 64
#define L_ 512
#define H_ 1024
#define EPS_ 1e-13f

typedef unsigned short u16;
typedef __attribute__((ext_vector_type(8))) short s16x8;
typedef __attribute__((ext_vector_type(4))) float f32x4;

__device__ __forceinline__ u16 f2bf(float f) {
  __hip_bfloat16 h = __float2bfloat16(f);
  union { __hip_bfloat16 h; u16 u; } c; c.h = h; return c.u;
}

// ---- Kernel 1: fused pre-pass. Blocks [0,8192): softmax rows -> W bf16.
//      Blocks [8192,16384): transpose+convert X f32 [B,L,H] -> XT bf16 [B,H,L].
__global__ __launch_bounds__(256) void prepass(const float* __restrict__ att,
                                               const float* __restrict__ mask,
                                               const float* __restrict__ X,
                                               u16* __restrict__ Wout,
                                               u16* __restrict__ XT) {
  const int bid = blockIdx.x;
  const int t = threadIdx.x;
  if (bid < 8192) {
    // ---- softmax: 4 rows/block, 1 wave/row ----
    const int row = bid * 4 + (t >> 6);
    const int l = t & 63;
    const size_t base = (size_t)row * L_;
    float4 v0 = *(const float4*)(att + base + l * 8);
    float4 v1 = *(const float4*)(att + base + l * 8 + 4);
    float a[8] = {v0.x, v0.y, v0.z, v0.w, v1.x, v1.y, v1.z, v1.w};
    float m = a[0];
#pragma unroll
    for (int j = 1; j < 8; ++j) m = fmaxf(m, a[j]);
#pragma unroll
    for (int off = 32; off > 0; off >>= 1) m = fmaxf(m, __shfl_xor(m, off));
    float e[8], z = 0.f;
#pragma unroll
    for (int j = 0; j < 8; ++j) { e[j] = __expf(a[j] - m); z += e[j]; }
#pragma unroll
    for (int off = 32; off > 0; off >>= 1) z += __shfl_xor(z, off);
    const float mk = mask[row];
    const float c = (1.0f / z) * (mk / (mk + EPS_));  // softmax row-sum == 1
    union { u16 u[8]; uint4 v; } w;
#pragma unroll
    for (int j = 0; j < 8; ++j) w.u[j] = f2bf(e[j] * c);
    *(uint4*)(Wout + base + l * 8) = w.v;
  } else {
    // ---- transpose 64x64 tile ----
    const int b2 = bid - 8192;
    const int lt = b2 & 7;
    const int ht = (b2 >> 3) & 15;
    const int b = b2 >> 7;
    const int l0 = lt * 64, h0 = ht * 64;
    __shared__ __align__(16) u16 tile[64 * 64];
    const int cg = t & 7;
    const int rr = t >> 3;
#pragma unroll
    for (int it = 0; it < 2; ++it) {
      int r = rr + it * 32;
      size_t gidx = ((size_t)(b * L_ + l0 + r)) * H_ + h0 + cg * 8;
      float4 u0 = *(const float4*)(X + gidx);
      float4 u1 = *(const float4*)(X + gidx + 4);
      union { u16 u[8]; uint4 v; } w;
      w.u[0] = f2bf(u0.x); w.u[1] = f2bf(u0.y); w.u[2] = f2bf(u0.z); w.u[3] = f2bf(u0.w);
      w.u[4] = f2bf(u1.x); w.u[5] = f2bf(u1.y); w.u[6] = f2bf(u1.z); w.u[7] = f2bf(u1.w);
      int g = cg ^ (r & 7) ^ ((r >> 3) & 7);
      *(uint4*)&tile[r * 64 + g * 8] = w.v;
    }
    __syncthreads();
#pragma unroll
    for (int it = 0; it < 2; ++it) {
      int hc = rr + it * 32;
      union { u16 u[8]; uint4 v; } e;
#pragma unroll
      for (int m2 = 0; m2 < 8; ++m2) {
        int r = cg * 8 + m2;
        int g = (hc >> 3) ^ (r & 7) ^ ((r >> 3) & 7);
        e.u[m2] = tile[r * 64 + g * 8 + (hc & 7)];
      }
      *(uint4*)(XT + ((size_t)(b * H_ + h0 + hc)) * L_ + l0 + cg * 8) = e.v;
    }
  }
}

#define GLOAD(gp, lp)                                                              \
  __builtin_amdgcn_global_load_lds((const __attribute__((address_space(1))) unsigned*)(gp), \
                                   (__attribute__((address_space(3))) unsigned*)(void*)(lp), 16, 0, 0)

// ---- Kernel 2: batched GEMM out = W @ X via XT. 256x256 tile, 8 waves.
// Deep pipeline: BK=32, 4-region LDS ring (128 KB), depth-3 prefetch,
// ONE barrier + counted vmcnt(8) per K-tile (T3+T4), setprio around MFMA (T5),
// 2-way-max XOR swizzle slot^=(r&3)^((r>>2)&3) on gload-source + ds_read (T2).
__global__ __launch_bounds__(512, 2) void gemm_bt(const u16* __restrict__ Wm,
                                                  const u16* __restrict__ XT,
                                                  float* __restrict__ out) {
  const int K = L_;     // 512
  const int NT = 16;    // K / 32
  // XCD swizzle: grid=512, bijective; one batch's 8 blocks share an XCD L2.
  const int swz = (blockIdx.x & 7) * 64 + (blockIdx.x >> 3);
  const int b  = swz >> 3;
  const int mt = (swz >> 2) & 1;
  const int nt = swz & 3;

  __shared__ __align__(16) char lds[4 * 32768];  // region: A 16KB @+0, B 16KB @+16384

  const int t = threadIdx.x;
  const int lane = t & 63;
  const int w = t >> 6;
  const int wm = w >> 2, wn = w & 3;  // 2x4 waves, 128x64 out each

  const u16* gA = Wm + ((size_t)b * L_ + mt * 256) * K;
  const u16* gB = XT + ((size_t)b * H_ + nt * 256) * K;

  // staging: thread t covers row r0=t>>2 (and r0+128), 16B slot t&3, both A and B.
  const int r0 = t >> 2;
  const int xsw = ((r0 & 3) ^ ((r0 >> 2) & 3));        // same for r0 and r0+128
  const int scol = ((t & 3) ^ xsw) * 8;                 // swizzled source col (elems)
  const u16* pA0 = gA + (size_t)r0 * K + scol;
  const u16* pB0 = gB + (size_t)r0 * K + scol;
  char* dA = lds + w * 1024;            // + rgn*32768 + p*8192
  char* dB = lds + 16384 + w * 1024;

  // ds_read frag byte offsets (within a region)
  int offA[8], offB[4];
#pragma unroll
  for (int mf = 0; mf < 8; ++mf) {
    int r = wm * 128 + mf * 16 + (lane & 15);
    offA[mf] = r * 64 + ((((lane >> 4) ^ (r & 3) ^ ((r >> 2) & 3))) << 4);
  }
#pragma unroll
  for (int nf = 0; nf < 4; ++nf) {
    int r = wn * 64 + nf * 16 + (lane & 15);
    offB[nf] = 16384 + r * 64 + ((((lane >> 4) ^ (r & 3) ^ ((r >> 2) & 3))) << 4);
  }

  f32x4 acc[8][4] = {};

#define STAGE(tt)                                                  \
  do {                                                             \
    const int _rg = (tt) & 3;                                      \
    const int _kt = (tt) * 32;                                     \
    GLOAD(pA0 + _kt, dA + _rg * 32768);                            \
    GLOAD(pA0 + _kt + 128 * K, dA + _rg * 32768 + 8192);           \
    GLOAD(pB0 + _kt, dB + _rg * 32768);                            \
    GLOAD(pB0 + _kt + 128 * K, dB + _rg * 32768 + 8192);           \
  } while (0)

  // prologue: 3 tiles in flight
  STAGE(0); STAGE(1); STAGE(2);
  asm volatile("s_waitcnt vmcnt(8)" ::: "memory");  // tile 0 resident
  __builtin_amdgcn_s_barrier();

#pragma unroll
  for (int k = 0; k < NT; ++k) {
    if (k + 3 < NT) STAGE(k + 3);  // dest = buf (k-1)&3, freed last iter

    const char* base = lds + (k & 3) * 32768;
    s16x8 af[8], bf4[4];
#pragma unroll
    for (int mf = 0; mf < 8; ++mf) af[mf] = *(const s16x8*)(base + offA[mf]);
#pragma unroll
    for (int nf = 0; nf < 4; ++nf) bf4[nf] = *(const s16x8*)(base + offB[nf]);
    asm volatile("s_waitcnt lgkmcnt(0)" ::: "memory");  // reads done before others restage

    __builtin_amdgcn_s_setprio(1);
#pragma unroll
    for (int mf = 0; mf < 8; ++mf)
#pragma unroll
      for (int nf = 0; nf < 4; ++nf)
        acc[mf][nf] = __builtin_amdgcn_mfma_f32_16x16x32_bf16(af[mf], bf4[nf], acc[mf][nf], 0, 0, 0);
    __builtin_amdgcn_s_setprio(0);

    // tile k+1 must be resident before next iter's ds_reads; keep later loads in flight
    if (k < NT - 3)       asm volatile("s_waitcnt vmcnt(8)" ::: "memory");
    else if (k == NT - 3) asm volatile("s_waitcnt vmcnt(4)" ::: "memory");
    else if (k == NT - 2) asm volatile("s_waitcnt vmcnt(0)" ::: "memory");
    if (k < NT - 1) __builtin_amdgcn_s_barrier();
  }
#undef STAGE

  // C/D layout: col=lane&15, row=(lane>>4)*4+reg  [verified m89/m91]
  const int orow0 = mt * 256 + wm * 128 + ((lane >> 4) << 2);
  const int ocol0 = nt * 256 + wn * 64 + (lane & 15);
#pragma unroll
  for (int mf = 0; mf < 8; ++mf)
#pragma unroll
    for (int nf = 0; nf < 4; ++nf)
#pragma unroll
      for (int j = 0; j < 4; ++j) {
        int row = orow0 + mf * 16 + j;
        int col = ocol0 + nf * 16;
        out[((size_t)b * L_ + row) * H_ + col] = acc[mf][nf][j];
      }
}

extern "C" void kernel_launch(void* const* d_in, const int* in_sizes, int n_in,
                              void* d_out, int out_size, void* d_ws, size_t ws_size,
                              hipStream_t stream) {
  (void)in_sizes; (void)n_in; (void)out_size; (void)ws_size;
  const float* sent = (const float*)d_in[0];  // [B, L, H] f32
  const float* mask = (const float*)d_in[1];  // [B, L]    f32
  const float* att  = (const float*)d_in[2];  // [B, L, L] f32
  u16* Wm = (u16*)d_ws;                       // [B, L, L] bf16 (32 MiB)
  u16* XT = Wm + (size_t)B_ * L_ * L_;        // [B, H, L] bf16 (64 MiB)
  float* outp = (float*)d_out;                // [B, L, H] f32

  prepass<<<16384, 256, 0, stream>>>(att, mask, sent, Wm, XT);
  gemm_bt<<<B_ * 2 * 4, 512, 0, stream>>>(Wm, XT, outp);
}